// Round 2
// baseline (468.855 us; speedup 1.0000x reference)
//
#include <hip/hip_runtime.h>
#include <hip/hip_bf16.h>

// Per-token-group (G=128) fp8-range quantization:
//   y = clip(x / (max(amax,1e-4)/448), -448, 448)  [fp32], scale = amax/448.
//   d_out = [ y (MN fp32) | scale (MN/128 fp32) ].
//
// V3 (streaming stores): V2 structure, plus
//  * __builtin_nontemporal_store for y (258 MB write stream would otherwise
//    evict the 128 MB input from L3 / thrash per-XCD L2; it is never re-read)
//  * exact-division grid: per-block iteration count precomputed, no per-iter
//    bounds check in the hot loop
// Verified-unchanged: 16-lane sub-wave per group, 16 B bf16 load per lane,
// 4-step __shfl_xor amax reduce, 2x float4 stores, dtype vote.

static constexpr float FP8_MAX_F  = 448.0f;
static constexpr float AMAX_FLOOR = 1e-4f;

typedef float floatx4 __attribute__((ext_vector_type(4)));

__global__ __launch_bounds__(256) void quant_v3_kernel(
    const void* __restrict__ xraw,
    float* __restrict__ y,
    float* __restrict__ scale,
    long long n_groups,
    int iters)                 // tiles per block (grid divides tiles exactly)
{
    __shared__ int flag_s;

    // --- input dtype vote (same 64 words for every block; L3-resident) ---
    if (threadIdx.x < 64) {
        const unsigned int w  = ((const unsigned int*)xraw)[threadIdx.x];
        const bool lo_nonzero = (w & 0xffffu) != 0u;   // true => packed bf16
        unsigned long long m  = __ballot(lo_nonzero);
        if (threadIdx.x == 0) flag_s = (__popcll(m) >= 32) ? 1 : 0;
    }
    __syncthreads();
    const bool in_bf16 = (flag_s != 0);

    const int lane16 = threadIdx.x & 15;   // position within the group (8 elems each)
    const int gsub   = threadIdx.x >> 4;   // which of the 16 groups this block-iter

    long long tile = blockIdx.x;
    for (int it = 0; it < iters; ++it, tile += gridDim.x) {
        const long long gid  = tile * 16 + gsub;
        const long long base = gid * 128 + (long long)lane16 * 8;  // element offset

        float v[8];
        if (in_bf16) {
            // 16 B = 8 bf16. base*2 bytes is 16B-aligned (base % 8 == 0).
            const int4 raw = *(const int4*)((const __hip_bfloat16*)xraw + base);
            const unsigned int* wp = (const unsigned int*)&raw;
#pragma unroll
            for (int i = 0; i < 4; ++i) {
                const unsigned int w = wp[i];
                v[2 * i]     = __uint_as_float((w & 0xffffu) << 16);  // low bf16
                v[2 * i + 1] = __uint_as_float(w & 0xffff0000u);      // high bf16
            }
        } else {
            const floatx4 a = ((const floatx4*)((const float*)xraw + base))[0];
            const floatx4 b = ((const floatx4*)((const float*)xraw + base))[1];
            v[0] = a.x; v[1] = a.y; v[2] = a.z; v[3] = a.w;
            v[4] = b.x; v[5] = b.y; v[6] = b.z; v[7] = b.w;
        }

        // --- per-lane abs-max over 8, then 16-lane butterfly reduce ---
        float m = fabsf(v[0]);
#pragma unroll
        for (int i = 1; i < 8; ++i) m = fmaxf(m, fabsf(v[i]));
        m = fmaxf(m, __shfl_xor(m, 1));
        m = fmaxf(m, __shfl_xor(m, 2));
        m = fmaxf(m, __shfl_xor(m, 4));
        m = fmaxf(m, __shfl_xor(m, 8));

        const float amax = fmaxf(m, AMAX_FLOOR);
        const float s    = amax * (1.0f / FP8_MAX_F);
        const float inv  = FP8_MAX_F / amax;   // same numerics as verified V1/V2

        floatx4 o0, o1;
        o0.x = fminf(fmaxf(v[0] * inv, -FP8_MAX_F), FP8_MAX_F);
        o0.y = fminf(fmaxf(v[1] * inv, -FP8_MAX_F), FP8_MAX_F);
        o0.z = fminf(fmaxf(v[2] * inv, -FP8_MAX_F), FP8_MAX_F);
        o0.w = fminf(fmaxf(v[3] * inv, -FP8_MAX_F), FP8_MAX_F);
        o1.x = fminf(fmaxf(v[4] * inv, -FP8_MAX_F), FP8_MAX_F);
        o1.y = fminf(fmaxf(v[5] * inv, -FP8_MAX_F), FP8_MAX_F);
        o1.z = fminf(fmaxf(v[6] * inv, -FP8_MAX_F), FP8_MAX_F);
        o1.w = fminf(fmaxf(v[7] * inv, -FP8_MAX_F), FP8_MAX_F);

        // Streaming stores: y is write-once, never re-read -> keep it out of
        // L2/L3 so the input read stream stays cached.
        __builtin_nontemporal_store(o0, (floatx4*)(y + base));
        __builtin_nontemporal_store(o1, (floatx4*)(y + base) + 1);

        if (lane16 == 0) __builtin_nontemporal_store(s, scale + gid);
    }
}

extern "C" void kernel_launch(void* const* d_in, const int* in_sizes, int n_in,
                              void* d_out, int out_size, void* d_ws, size_t ws_size,
                              hipStream_t stream) {
    const long long MN = (long long)in_sizes[0];   // M*N elements, divisible by 128
    const long long n_groups = MN / 128;

    float* y     = (float*)d_out;
    float* scale = y + MN;                         // outputs concatenated: y then scale

    const int threads = 256;                       // 4 waves; 16 groups per iteration
    const long long tiles = (n_groups + 15) / 16;

    // Pick the largest grid <= 2048 that divides tiles exactly (for the
    // benchmark shape: tiles = 32768, blocks = 2048, iters = 16).
    long long blocks = tiles < 2048 ? tiles : 2048;
    while (tiles % blocks != 0) --blocks;          // terminates at 1 worst-case
    const int iters = (int)(tiles / blocks);

    quant_v3_kernel<<<(int)blocks, threads, 0, stream>>>(d_in[0], y, scale,
                                                         n_groups, iters);
}

// Round 3
// 441.798 us; speedup vs baseline: 1.0612x; 1.0612x over previous
//
#include <hip/hip_runtime.h>
#include <hip/hip_bf16.h>

// Per-token-group (G=128) fp8-range quantization:
//   y = clip(x / (max(amax,1e-4)/448), -448, 448)  [fp32], scale = amax/448.
//   d_out = [ y (MN fp32) | scale (MN/128 fp32) ].
//
// V4 (MLP=4): V2 structure (nt stores REVERTED — V3 post-mortem: nt scale
// stores cost +52 MB HBM writes and +15 us; there is no reuse to protect).
// New: 4-tile manual unroll with all 4 group-loads issued before first use,
// so s_waitcnt becomes vmcnt(3..0) and the ~900-cycle HBM latency is
// amortized over 4 tiles (kernel was latency-bound at MLP=1: 2.45 TB/s,
// VALUBusy 5.6%).

static constexpr float FP8_MAX_F  = 448.0f;
static constexpr float AMAX_FLOOR = 1e-4f;

typedef float floatx4 __attribute__((ext_vector_type(4)));

__device__ __forceinline__ void process_group(const float v[8],
                                              float* __restrict__ y,
                                              float* __restrict__ scale,
                                              long long base, long long gid,
                                              int lane16)
{
    // per-lane abs-max over 8, then 16-lane butterfly reduce (xor 1,2,4,8)
    float m = fabsf(v[0]);
#pragma unroll
    for (int i = 1; i < 8; ++i) m = fmaxf(m, fabsf(v[i]));
    m = fmaxf(m, __shfl_xor(m, 1));
    m = fmaxf(m, __shfl_xor(m, 2));
    m = fmaxf(m, __shfl_xor(m, 4));
    m = fmaxf(m, __shfl_xor(m, 8));

    const float amax = fmaxf(m, AMAX_FLOOR);
    const float s    = amax * (1.0f / FP8_MAX_F);
    const float inv  = FP8_MAX_F / amax;   // same numerics as verified V1/V2

    floatx4 o0, o1;
    o0.x = fminf(fmaxf(v[0] * inv, -FP8_MAX_F), FP8_MAX_F);
    o0.y = fminf(fmaxf(v[1] * inv, -FP8_MAX_F), FP8_MAX_F);
    o0.z = fminf(fmaxf(v[2] * inv, -FP8_MAX_F), FP8_MAX_F);
    o0.w = fminf(fmaxf(v[3] * inv, -FP8_MAX_F), FP8_MAX_F);
    o1.x = fminf(fmaxf(v[4] * inv, -FP8_MAX_F), FP8_MAX_F);
    o1.y = fminf(fmaxf(v[5] * inv, -FP8_MAX_F), FP8_MAX_F);
    o1.z = fminf(fmaxf(v[6] * inv, -FP8_MAX_F), FP8_MAX_F);
    o1.w = fminf(fmaxf(v[7] * inv, -FP8_MAX_F), FP8_MAX_F);

    ((floatx4*)(y + base))[0] = o0;
    ((floatx4*)(y + base))[1] = o1;

    if (lane16 == 0) scale[gid] = s;
}

__device__ __forceinline__ void decode_bf16(const int4 raw, float v[8])
{
    const unsigned int* wp = (const unsigned int*)&raw;
#pragma unroll
    for (int i = 0; i < 4; ++i) {
        const unsigned int w = wp[i];
        v[2 * i]     = __uint_as_float((w & 0xffffu) << 16);  // low bf16
        v[2 * i + 1] = __uint_as_float(w & 0xffff0000u);      // high bf16
    }
}

__global__ __launch_bounds__(256) void quant_v4_kernel(
    const void* __restrict__ xraw,
    float* __restrict__ y,
    float* __restrict__ scale,
    long long n_groups,
    int iters)                 // tiles per block (grid divides tiles exactly)
{
    __shared__ int flag_s;

    // --- input dtype vote (same 64 words for every block; L3-resident) ---
    if (threadIdx.x < 64) {
        const unsigned int w  = ((const unsigned int*)xraw)[threadIdx.x];
        const bool lo_nonzero = (w & 0xffffu) != 0u;   // true => packed bf16
        unsigned long long m  = __ballot(lo_nonzero);
        if (threadIdx.x == 0) flag_s = (__popcll(m) >= 32) ? 1 : 0;
    }
    __syncthreads();
    const bool in_bf16 = (flag_s != 0);

    const int lane16 = threadIdx.x & 15;   // position within the group (8 elems each)
    const int gsub   = threadIdx.x >> 4;   // which of the 16 groups this block-iter
    const long long tstride = gridDim.x;

    long long tile = blockIdx.x;
    int it = 0;

    if (in_bf16) {
        // ---- main loop: 4 tiles, loads hoisted (MLP = 4) ----
        for (; it + 4 <= iters; it += 4) {
            long long base[4];
            int4 raw[4];
#pragma unroll
            for (int u = 0; u < 4; ++u) {
                const long long gid = (tile + (long long)u * tstride) * 16 + gsub;
                base[u] = gid * 128 + (long long)lane16 * 8;
                raw[u] = *(const int4*)((const __hip_bfloat16*)xraw + base[u]);
            }
#pragma unroll
            for (int u = 0; u < 4; ++u) {
                const long long gid = (tile + (long long)u * tstride) * 16 + gsub;
                float v[8];
                decode_bf16(raw[u], v);
                process_group(v, y, scale, base[u], gid, lane16);
            }
            tile += 4 * tstride;
        }
        // ---- remainder ----
        for (; it < iters; ++it, tile += tstride) {
            const long long gid  = tile * 16 + gsub;
            const long long base = gid * 128 + (long long)lane16 * 8;
            float v[8];
            decode_bf16(*(const int4*)((const __hip_bfloat16*)xraw + base), v);
            process_group(v, y, scale, base, gid, lane16);
        }
    } else {
        // ---- fp32 fallback path (safety net; same structure, MLP = 4) ----
        for (; it + 4 <= iters; it += 4) {
            long long base[4];
            floatx4 ra[4], rb[4];
#pragma unroll
            for (int u = 0; u < 4; ++u) {
                const long long gid = (tile + (long long)u * tstride) * 16 + gsub;
                base[u] = gid * 128 + (long long)lane16 * 8;
                ra[u] = ((const floatx4*)((const float*)xraw + base[u]))[0];
                rb[u] = ((const floatx4*)((const float*)xraw + base[u]))[1];
            }
#pragma unroll
            for (int u = 0; u < 4; ++u) {
                const long long gid = (tile + (long long)u * tstride) * 16 + gsub;
                float v[8] = {ra[u].x, ra[u].y, ra[u].z, ra[u].w,
                              rb[u].x, rb[u].y, rb[u].z, rb[u].w};
                process_group(v, y, scale, base[u], gid, lane16);
            }
            tile += 4 * tstride;
        }
        for (; it < iters; ++it, tile += tstride) {
            const long long gid  = tile * 16 + gsub;
            const long long base = gid * 128 + (long long)lane16 * 8;
            const floatx4 a = ((const floatx4*)((const float*)xraw + base))[0];
            const floatx4 b = ((const floatx4*)((const float*)xraw + base))[1];
            float v[8] = {a.x, a.y, a.z, a.w, b.x, b.y, b.z, b.w};
            process_group(v, y, scale, base, gid, lane16);
        }
    }
}

extern "C" void kernel_launch(void* const* d_in, const int* in_sizes, int n_in,
                              void* d_out, int out_size, void* d_ws, size_t ws_size,
                              hipStream_t stream) {
    const long long MN = (long long)in_sizes[0];   // M*N elements, divisible by 128
    const long long n_groups = MN / 128;

    float* y     = (float*)d_out;
    float* scale = y + MN;                         // outputs concatenated: y then scale

    const int threads = 256;                       // 4 waves; 16 groups per iteration
    const long long tiles = (n_groups + 15) / 16;

    // Largest grid <= 2048 dividing tiles exactly (bench shape: 32768 tiles
    // -> 2048 blocks x 16 iters). No per-iter bounds check needed.
    long long blocks = tiles < 2048 ? tiles : 2048;
    while (tiles % blocks != 0) --blocks;          // terminates at 1 worst-case
    const int iters = (int)(tiles / blocks);

    quant_v4_kernel<<<(int)blocks, threads, 0, stream>>>(d_in[0], y, scale,
                                                         n_groups, iters);
}